// Round 6
// baseline (76.740 us; speedup 1.0000x reference)
//
#include <hip/hip_runtime.h>
#include <math.h>

#define NROWS 16384

__device__ __forceinline__ float prod8(float x) {
    return ((x * (x + 1.f)) * ((x + 2.f) * (x + 3.f))) *
           (((x + 4.f) * (x + 5.f)) * ((x + 6.f) * (x + 7.f)));
}

// logGamma(x), push-up-by-8 Stirling; abs err ~1e-5 on (0, 4200]
__device__ __forceinline__ float lgam(float x) {
    float z  = x + 8.f;
    float lz = __logf(z);
    float zi = __builtin_amdgcn_rcpf(z);
    return (z - 0.5f) * lz - z + 0.91893853f + 0.08333333f * zi - __logf(prod8(x));
}

// logGamma(a) - logGamma(b); constant cancels.
__device__ __forceinline__ float lgam_diff(float a, float b) {
    float za = a + 8.f, zb = b + 8.f;
    float la = __logf(za), lb = __logf(zb);
    float ra = __builtin_amdgcn_rcpf(za), rb = __builtin_amdgcn_rcpf(zb);
    return (za - 0.5f) * la - (zb - 0.5f) * lb - (a - b)
         + 0.08333333f * (ra - rb)
         + __logf(prod8(b) * __builtin_amdgcn_rcpf(prod8(a)));
}

// DPP add with compile-time ctrl (builtin requires constant integer).
template <int CTRL>
__device__ __forceinline__ float dpp_add(float v) {
    int t = __builtin_amdgcn_update_dpp(0, __float_as_int(v), CTRL, 0xf, 0xf, true);
    return v + __int_as_float(t);
}
// After this: lane31 = sum(lanes 0..31), lane63 = sum(lanes 32..63). Pure VALU.
__device__ __forceinline__ float half_reduce(float v) {
    v = dpp_add<0x111>(v);  // row_shr:1
    v = dpp_add<0x112>(v);  // row_shr:2
    v = dpp_add<0x114>(v);  // row_shr:4
    v = dpp_add<0x118>(v);  // row_shr:8
    v = dpp_add<0x142>(v);  // row_bcast:15
    return v;
}

__device__ __forceinline__ float copula_nll(float u1, float u2, float th,
                                            float lp1, float lp2) {
    const float theta = fmaxf(fmaxf(th, 0.f) + 1.f, 1.00001f);
    const float x1 = -__logf(u1);
    const float x2 = -__logf(u2);
    const float t1 = __expf(theta * __logf(x1));
    const float t2 = __expf(theta * __logf(x2));
    const float logc = -__expf(__logf(t1 + t2) * __builtin_amdgcn_rcpf(theta));
    return -(lp1 + lp2 + logc);
}

// One wave per TWO rows (ILP): 8192 independent waves, no mid-kernel coupling.
// Per row: lanes 0-31 margin 0, lanes 32-63 margin 1 (32-way chunked CDF).
// Truncation K = min(mode + 6*sigma + 16, y): tail-mass error <= ~5e-3 in u
// only when u~1 -> logc error ~5e-3/row << 2% output threshold.
__global__ __launch_bounds__(256) void nb_rows(
    const float* __restrict__ r,
    const float* __restrict__ p,
    const int*   __restrict__ tg,
    float* __restrict__ partial)   // one partial sum per block (2048)
{
    __shared__ float sb[4];
    const int tid  = threadIdx.x;
    const int w    = tid >> 6;
    const int lane = tid & 63;
    const int wid  = blockIdx.x * 4 + w;   // global wave id < 8192
    const int j    = lane >> 5;            // margin
    const int sl   = lane & 31;            // sub-lane in margin half
    const int b4   = 4 * wid;              // rows 2*wid, 2*wid+1

    // ---- loads (broadcast within half-waves) ----
    const float rA  = fmaxf(r[b4 + j], 1e-4f);
    const float rB  = fmaxf(r[b4 + 2 + j], 1e-4f);
    const float p0A = p[b4],     p0B = p[b4 + 2];
    const float thA = p[b4 + 1], thB = p[b4 + 3];
    const int   yA  = tg[b4 + j], yB = tg[b4 + 2 + j];
    const float yAf = (float)yA,  yBf = (float)yB;

    // ---- two independent chains, straight-line for ILP ----
    const float e2A = __expf(2.f * p0A), e2B = __expf(2.f * p0B);
    const float p1A = fminf(fmaxf(1.f - 2.f * __builtin_amdgcn_rcpf(e2A + 1.f), 1e-4f), 0.9999f);
    const float p1B = fminf(fmaxf(1.f - 2.f * __builtin_amdgcn_rcpf(e2B + 1.f), 1e-4f), 0.9999f);
    const float qA  = 1.f - p1A,  qB  = 1.f - p1B;
    const float lpA = __logf(p1A), lpB = __logf(p1B);
    const float baseA = rA * __logf(qA) - lgam(rA);
    const float baseB = rB * __logf(qB) - lgam(rB);

    const float qiA = __builtin_amdgcn_rcpf(qA), qiB = __builtin_amdgcn_rcpf(qB);
    const float rpA = rA * p1A, rpB = rB * p1B;
    const int KA = (int)fminf(fmaf(6.f, __fsqrt_rn(rpA) * qiA, rpA * qiA) + 16.f, yAf);
    const int KB = (int)fminf(fmaf(6.f, __fsqrt_rn(rpB) * qiB, rpB * qiB) + 16.f, yBf);

    const int cA = (KA + 32) >> 5, cB = (KB + 32) >> 5;
    const int sA = sl * cA,        sB = sl * cB;

    float accA = 0.f, pmfA = 0.f, kfA = 0.f, pkA = 0.f;
    float accB = 0.f, pmfB = 0.f, kfB = 0.f, pkB = 0.f;
    int cntA = 0, cntB = 0;
    if (sA <= KA) {
        cntA = min(cA, KA + 1 - sA);
        const float sf = (float)sA;
        pmfA = __expf(lgam_diff(sf + rA, sf + 1.f) + baseA + sf * lpA);
        accA = pmfA;  kfA = sf + 1.f;  pkA = p1A * (sf + rA);
    }
    if (sB <= KB) {
        cntB = min(cB, KB + 1 - sB);
        const float sf = (float)sB;
        pmfB = __expf(lgam_diff(sf + rB, sf + 1.f) + baseB + sf * lpB);
        accB = pmfB;  kfB = sf + 1.f;  pkB = p1B * (sf + rB);
    }

    // fused recurrence loop (both rows advance per iteration -> ILP)
    const int mmax = max(cntA, cntB);
    for (int m = 1; m < mmax; ++m) {
        if (m < cntA) {
            pmfA *= pkA * __builtin_amdgcn_rcpf(kfA);
            accA += pmfA;  pkA += p1A;  kfA += 1.f;
        }
        if (m < cntB) {
            pmfB *= pkB * __builtin_amdgcn_rcpf(kfB);
            accB += pmfB;  pkB += p1B;  kfB += 1.f;
        }
    }

    // half-wave sums via DPP (lane31 = margin0, lane63 = margin1)
    float uA = half_reduce(accA);
    float uB = half_reduce(accB);
    uA = fminf(fmaxf(uA, 1e-6f), 1.f - 1e-6f);
    uB = fminf(fmaxf(uB, 1e-6f), 1.f - 1e-6f);

    // exact log-pmf at k=y (half-uniform; overlaps with reduce)
    const float lpyA = lgam_diff(yAf + rA, yAf + 1.f) + baseA + yAf * lpA;
    const float lpyB = lgam_diff(yBf + rB, yBf + 1.f) + baseB + yBf * lpB;

    const float uAo   = __shfl_xor(uA, 32);
    const float uBo   = __shfl_xor(uB, 32);
    const float lpyAo = __shfl_xor(lpyA, 32);
    const float lpyBo = __shfl_xor(lpyB, 32);

    if (lane == 31) {   // has margin0 sums + shuffled margin1 values
        sb[w] = copula_nll(uA, uAo, thA, lpyA, lpyAo)
              + copula_nll(uB, uBo, thB, lpyB, lpyBo);
    }
    __syncthreads();
    if (tid == 0)
        partial[blockIdx.x] = (sb[0] + sb[1]) + (sb[2] + sb[3]);
}

// 2048 partials -> mean
__global__ __launch_bounds__(1024) void reduce_p(
    const float* __restrict__ pp, float* __restrict__ out)
{
    __shared__ float sm[16];
    const int t = threadIdx.x;
    float a = pp[t] + pp[t + 1024];
    #pragma unroll
    for (int off = 32; off; off >>= 1) a += __shfl_xor(a, off);
    if ((t & 63) == 0) sm[t >> 6] = a;
    __syncthreads();
    if (t < 16) {
        float b = sm[t];
        b += __shfl_xor(b, 1);
        b += __shfl_xor(b, 2);
        b += __shfl_xor(b, 4);
        b += __shfl_xor(b, 8);
        if (t == 0) out[0] = b * (1.f / (float)NROWS);
    }
}

extern "C" void kernel_launch(void* const* d_in, const int* in_sizes, int n_in,
                              void* d_out, int out_size, void* d_ws, size_t ws_size,
                              hipStream_t stream) {
    const float* r  = (const float*)d_in[0];
    const float* p  = (const float*)d_in[1];
    const int*   tg = (const int*)d_in[2];
    float* out = (float*)d_out;
    float* partial = (float*)d_ws;   // 2048 floats = 8 KB << ws_size

    nb_rows<<<2048, 256, 0, stream>>>(r, p, tg, partial);
    reduce_p<<<1, 1024, 0, stream>>>(partial, out);
}